// Round 3
// baseline (2131.771 us; speedup 1.0000x reference)
//
#include <hip/hip_runtime.h>
#include <hip/hip_bf16.h>

#define AA 64
#define NBRF 41
#define ORIGD 92
#define NATOM 50000
#define MM 12
#define NB 1000
#define NPCC 50
#define NEDGE (NATOM*MM)
constexpr float EPS_BN = 1e-5f;

using bf16 = __hip_bfloat16;

__device__ __forceinline__ unsigned short f2bu(float f) {
    bf16 h = __float2bfloat16(f);
    return *reinterpret_cast<unsigned short*>(&h);
}
__device__ __forceinline__ float softplusf(float x) {
    return fmaxf(x, 0.f) + log1pf(expf(-fabsf(x)));
}
__device__ __forceinline__ float sigmoidf(float x) {
    return 1.f / (1.f + expf(-x));
}

// ---------------- zero small stats region ----------------
__global__ void k_zero(float* p, int n) {
    int i = blockIdx.x * blockDim.x + threadIdx.x;
    if (i < n) p[i] = 0.f;
}

// ---------------- embed: x = atom_fea @ emb_w  (N,92)@(92,64) ----------------
__global__ __launch_bounds__(256) void k_embed(const float* __restrict__ af,
                                               const float* __restrict__ w,
                                               float* __restrict__ x) {
    __shared__ float wl[ORIGD * AA];   // 23 KB
    __shared__ float al[4][ORIGD];
    int t = threadIdx.x;
    for (int i = t; i < ORIGD * AA; i += 256) wl[i] = w[i];
    int n0 = blockIdx.x * 4;
    for (int i = t; i < 4 * ORIGD; i += 256) {
        int a = i / ORIGD, k = i - a * ORIGD;
        al[a][k] = af[(size_t)(n0 + a) * ORIGD + k];
    }
    __syncthreads();
    int c = t & 63, a = t >> 6;
    float acc = 0.f;
    #pragma unroll 4
    for (int k = 0; k < ORIGD; ++k)
        acc += al[a][k] * wl[k * AA + c];
    x[(size_t)(n0 + a) * AA + c] = acc;
}

// ---------------- y0 = x@W[0:64], y1 = x@W[64:128] ----------------
__global__ __launch_bounds__(256) void k_y01(const float* __restrict__ x,
                                             const float* __restrict__ W, // 169x128 layer base
                                             float* __restrict__ y0, float* __restrict__ y1) {
    __shared__ float wl[64 * 128];  // 32 KB, one half at a time
    __shared__ float xl[16][AA];    // 4 KB
    int t = threadIdx.x;
    int n0 = blockIdx.x * 16;
    for (int i = t; i < 16 * AA; i += 256) {
        int a = i >> 6, k = i & 63;
        xl[a][k] = x[(size_t)(n0 + a) * AA + k];
    }
    int tc = t & 31, sub = t >> 5;
    int c0 = tc * 4;
    for (int half = 0; half < 2; ++half) {
        if (half) __syncthreads();   // previous compute must finish before wl overwrite
        const float* Wh = W + (size_t)half * 64 * 128;
        for (int i = t; i < 64 * 128; i += 256) wl[i] = Wh[i];
        __syncthreads();
        float* yout = half ? y1 : y0;
        for (int ah = 0; ah < 2; ++ah) {
            int a = sub + ah * 8;
            float a0=0,a1=0,a2=0,a3=0;
            #pragma unroll 8
            for (int k = 0; k < AA; ++k) {
                float xv = xl[a][k];
                float4 w = *reinterpret_cast<const float4*>(&wl[k * 128 + c0]);
                a0 += xv * w.x; a1 += xv * w.y; a2 += xv * w.z; a3 += xv * w.w;
            }
            float4 r = {a0,a1,a2,a3};
            *reinterpret_cast<float4*>(&yout[(size_t)(n0 + a) * 128 + c0]) = r;
        }
    }
}

// ---------------- pass A: r = y0 + y1[g] + nbr_fea@W2; stats; optional store ----------------
template<bool STORE>
__global__ __launch_bounds__(256) void k_passA(const float* __restrict__ y0, const float* __restrict__ y1,
                                               const float* __restrict__ nf,
                                               const int* __restrict__ nidx,
                                               const float* __restrict__ W2, // 41x128
                                               float* __restrict__ stats,    // [256]
                                               unsigned short* __restrict__ gated) {
    __shared__ float w2l[NBRF * 128];     // 21 KB
    __shared__ float fl[16 * MM * NBRF];  // 31.5 KB
    __shared__ int il[16 * MM];
    int t = threadIdx.x;
    int n0 = blockIdx.x * 16;
    for (int i = t; i < NBRF * 128; i += 256) w2l[i] = W2[i];
    {
        const float* fg = nf + (size_t)n0 * MM * NBRF;
        for (int i = t; i < 16 * MM * NBRF; i += 256) fl[i] = fg[i];
        const int* ig = nidx + n0 * MM;
        for (int i = t; i < 16 * MM; i += 256) il[i] = ig[i];
    }
    __syncthreads();
    int tc = t & 31, sub = t >> 5;
    int c0 = tc * 4;
    float s0=0,s1=0,s2=0,s3=0, q0=0,q1=0,q2=0,q3=0;
    for (int e = sub; e < 16 * MM; e += 8) {
        int na = e / MM;
        int g = il[e];
        float z0=0,z1=0,z2=0,z3=0;
        const float* fe = &fl[e * NBRF];
        #pragma unroll
        for (int k = 0; k < NBRF; ++k) {
            float fv = fe[k];
            float4 w = *reinterpret_cast<const float4*>(&w2l[k * 128 + c0]);
            z0 += fv * w.x; z1 += fv * w.y; z2 += fv * w.z; z3 += fv * w.w;
        }
        float4 v0 = *reinterpret_cast<const float4*>(&y0[(size_t)(n0 + na) * 128 + c0]);
        float4 v1 = *reinterpret_cast<const float4*>(&y1[(size_t)g * 128 + c0]);
        float r0 = z0 + v0.x + v1.x;
        float r1 = z1 + v0.y + v1.y;
        float r2 = z2 + v0.z + v1.z;
        float r3 = z3 + v0.w + v1.w;
        s0 += r0; s1 += r1; s2 += r2; s3 += r3;
        q0 += r0*r0; q1 += r1*r1; q2 += r2*r2; q3 += r3*r3;
        if (STORE) {
            ushort4 u;
            u.x = f2bu(r0); u.y = f2bu(r1); u.z = f2bu(r2); u.w = f2bu(r3);
            *reinterpret_cast<ushort4*>(&gated[((size_t)(n0 * MM) + e) * 128 + c0]) = u;
        }
    }
    __syncthreads();
    float* red = fl; // reuse
    int base = t * 8;
    red[base+0]=s0; red[base+1]=s1; red[base+2]=s2; red[base+3]=s3;
    red[base+4]=q0; red[base+5]=q1; red[base+6]=q2; red[base+7]=q3;
    __syncthreads();
    if (t < 32) {
        float a[8] = {0,0,0,0,0,0,0,0};
        for (int s = 0; s < 8; ++s)
            for (int j = 0; j < 8; ++j) a[j] += red[(s * 32 + t) * 8 + j];
        int cb = t * 4;
        atomicAdd(&stats[cb+0], a[0]); atomicAdd(&stats[cb+1], a[1]);
        atomicAdd(&stats[cb+2], a[2]); atomicAdd(&stats[cb+3], a[3]);
        atomicAdd(&stats[128+cb+0], a[4]); atomicAdd(&stats[128+cb+1], a[5]);
        atomicAdd(&stats[128+cb+2], a[6]); atomicAdd(&stats[128+cb+3], a[7]);
    }
}

// ---------------- bn1 fold: scale/shift (fc bias cancels in BN) ----------------
__global__ void k_sc1(const float* __restrict__ stats, const float* __restrict__ g,
                      const float* __restrict__ b, float* __restrict__ sc) {
    int c = threadIdx.x; // 128
    float cnt = (float)NEDGE;
    float mean = stats[c] / cnt;
    float var = stats[128 + c] / cnt - mean * mean;
    float inv = rsqrtf(var + EPS_BN);
    float scale = g[c] * inv;
    sc[c] = scale;
    sc[128 + c] = b[c] - mean * scale;
}

// ---------------- pass B: summed = sum_m sig(rf)*sp(rc); bn2 stats ----------------
template<bool STORE>
__global__ __launch_bounds__(256) void k_passB(const float* __restrict__ y0, const float* __restrict__ y1,
                                               const float* __restrict__ nf,
                                               const int* __restrict__ nidx,
                                               const float* __restrict__ W2,
                                               const float* __restrict__ sc,
                                               const unsigned short* __restrict__ gated,
                                               float* __restrict__ summed,
                                               float* __restrict__ stats2) {
    __shared__ float smem[STORE ? 4096 : 13312];
    int t = threadIdx.x;
    int n0 = blockIdx.x * 16;
    int c = t & 63, who = t >> 6;
    float scF = sc[c],      shF = sc[128 + c];
    float scC = sc[64 + c], shC = sc[192 + c];
    float part[16];

    if constexpr (STORE) {
        for (int a = 0; a < 16; ++a) {
            float p = 0.f;
            for (int mi = 0; mi < 3; ++mi) {
                int m = who * 3 + mi;
                size_t row = ((size_t)((n0 + a) * MM + m)) * 128;
                float rf = __bfloat162float(*reinterpret_cast<const bf16*>(&gated[row + c])) * scF + shF;
                float rc = __bfloat162float(*reinterpret_cast<const bf16*>(&gated[row + 64 + c])) * scC + shC;
                p += sigmoidf(rf) * softplusf(rc);
            }
            part[a] = p;
        }
        __syncthreads();
    } else {
        float* fl = smem;                       // 7872
        float* w2p = smem + 7872;               // 5248, paired layout
        int* il = (int*)(smem + 7872 + 5248);   // 192
        const float* fg = nf + (size_t)n0 * MM * NBRF;
        for (int i = t; i < 16 * MM * NBRF; i += 256) fl[i] = fg[i];
        for (int i = t; i < NBRF * 128; i += 256) {
            int k = i >> 7, cg = i & 127;
            int cc = cg & 63, h = cg >> 6;
            w2p[(k * 64 + cc) * 2 + h] = W2[i];
        }
        const int* ig = nidx + n0 * MM;
        for (int i = t; i < 16 * MM; i += 256) il[i] = ig[i];
        __syncthreads();
        for (int a = 0; a < 16; ++a) {
            float p = 0.f;
            for (int mi = 0; mi < 3; ++mi) {
                int m = who * 3 + mi;
                int e = a * MM + m;
                int g = il[e];
                float zf = 0.f, zc = 0.f;
                const float* fe = &fl[e * NBRF];
                #pragma unroll
                for (int k = 0; k < NBRF; ++k) {
                    float fv = fe[k];
                    float2 w = *reinterpret_cast<const float2*>(&w2p[(k * 64 + c) * 2]);
                    zf += fv * w.x; zc += fv * w.y;
                }
                size_t r0 = (size_t)(n0 + a) * 128;
                size_t r1 = (size_t)g * 128;
                float rf = (zf + y0[r0 + c] + y1[r1 + c]) * scF + shF;
                float rc = (zc + y0[r0 + 64 + c] + y1[r1 + 64 + c]) * scC + shC;
                p += sigmoidf(rf) * softplusf(rc);
            }
            part[a] = p;
        }
        __syncthreads(); // fl dead, reuse as red
    }
    float* red = smem;
    for (int a = 0; a < 16; ++a) red[a * 256 + who * 64 + c] = part[a];
    __syncthreads();
    if (who == 0) {
        float sA = 0.f, qA = 0.f;
        for (int a = 0; a < 16; ++a) {
            float s = red[a * 256 + c] + red[a * 256 + 64 + c]
                    + red[a * 256 + 128 + c] + red[a * 256 + 192 + c];
            summed[(size_t)(n0 + a) * AA + c] = s;
            sA += s; qA += s * s;
        }
        atomicAdd(&stats2[c], sA);
        atomicAdd(&stats2[64 + c], qA);
    }
}

// ---------------- bn2 fold ----------------
__global__ void k_sc2(const float* __restrict__ stats2, const float* __restrict__ g,
                      const float* __restrict__ b, float* __restrict__ sc2) {
    int c = threadIdx.x; // 64
    float cnt = (float)NATOM;
    float mean = stats2[c] / cnt;
    float var = stats2[64 + c] / cnt - mean * mean;
    float inv = rsqrtf(var + EPS_BN);
    float scale = g[c] * inv;
    sc2[c] = scale;
    sc2[64 + c] = b[c] - mean * scale;
}

// ---------------- x = softplus(x + bn2(summed)) ----------------
__global__ void k_update(float* __restrict__ x, const float* __restrict__ summed,
                         const float* __restrict__ sc2) {
    int i = blockIdx.x * blockDim.x + threadIdx.x;
    if (i < NATOM * AA) {
        int c = i & 63;
        float s = summed[i] * sc2[c] + sc2[64 + c];
        x[i] = softplusf(x[i] + s);
    }
}

// ---------------- bilinear head: q, fc1, log_softmax ----------------
__global__ __launch_bounds__(256) void k_q(const float* __restrict__ x, const int* __restrict__ cidx,
                                           const float* __restrict__ adjw, // 6*64*64
                                           const float* __restrict__ adjb, // 6
                                           const float* __restrict__ fc1w, // 36
                                           const float* __restrict__ fc1b, // 6
                                           float* __restrict__ logp) {
    __shared__ float Ao[64 * 64];   // 16 KB, one o at a time
    __shared__ float cfl[16][64];
    __shared__ float qv[16][6];
    int t = threadIdx.x;
    int p0 = blockIdx.x * 16;
    int e = t & 63, who = t >> 6;
    for (int i = t; i < 16 * 64; i += 256) {
        int a = i >> 6, d = i & 63;
        cfl[a][d] = x[(size_t)cidx[p0 + a] * AA + d];
    }
    for (int o = 0; o < 6; ++o) {
        __syncthreads();  // prev-iter readers done (and cfl ready on first iter)
        for (int i = t; i < 4096; i += 256) Ao[i] = adjw[o * 4096 + i];
        __syncthreads();
        float bo = adjb[o];
        for (int aa = 0; aa < 4; ++aa) {
            int a = who * 4 + aa;
            float td = 0.f;
            #pragma unroll 8
            for (int d = 0; d < 64; ++d)
                td += cfl[a][d] * Ao[d * 64 + e];
            float v = td * cfl[a][e];
            for (int off = 32; off; off >>= 1) v += __shfl_down(v, off);
            if (e == 0) qv[a][o] = v + bo;
        }
    }
    __syncthreads();
    if (t < 16) {
        float q2[6];
        float mx = -1e30f;
        for (int o2 = 0; o2 < 6; ++o2) {
            float acc = fc1b[o2];
            for (int o = 0; o < 6; ++o) acc += qv[t][o] * fc1w[o * 6 + o2];
            q2[o2] = acc; mx = fmaxf(mx, acc);
        }
        float se = 0.f;
        for (int o2 = 0; o2 < 6; ++o2) se += expf(q2[o2] - mx);
        float lse = mx + logf(se);
        for (int o2 = 0; o2 < 6; ++o2) logp[(size_t)(p0 + t) * 6 + o2] = q2[o2] - lse;
    }
}

// ---------------- edge_prob broadcast write (fp32, float4-coalesced) ----------------
// Within batch b, the 15000-float output block is logp[b] (300 floats) repeated 50x.
__global__ void k_edge(const float* __restrict__ logp, float* __restrict__ out0) {
    int i4 = blockIdx.x * blockDim.x + threadIdx.x;
    if (i4 >= (NB * NPCC * NPCC * 6) / 4) return;
    int e = i4 * 4;
    int b = e / (NPCC * NPCC * 6);
    int rr = e - b * (NPCC * NPCC * 6);
    const float* lb = &logp[(size_t)b * NPCC * 6];
    float4 v;
    int r0 = rr % 300;
    v.x = lb[r0];
    int r1 = (rr + 1) % 300; v.y = lb[r1];
    int r2 = (rr + 2) % 300; v.z = lb[r2];
    int r3 = (rr + 3) % 300; v.w = lb[r3];
    *reinterpret_cast<float4*>(&out0[e]) = v;
}

// ---------------- atom_feature = cf @ af_w + af_b (fp32 out) ----------------
__global__ __launch_bounds__(256) void k_af(const float* __restrict__ x, const int* __restrict__ cidx,
                                            const float* __restrict__ afw, // 64*92
                                            const float* __restrict__ afb, // 92
                                            float* __restrict__ out1) {
    __shared__ float wl[AA * ORIGD]; // 23.5 KB
    __shared__ float cfl[2][AA];
    int t = threadIdx.x;
    for (int i = t; i < AA * ORIGD; i += 256) wl[i] = afw[i];
    int p0 = blockIdx.x * 2;
    if (t < 128) {
        int a = t >> 6, e = t & 63;
        cfl[a][e] = x[(size_t)cidx[p0 + a] * AA + e];
    }
    __syncthreads();
    int a = t >> 7, c = t & 127;
    if (c < ORIGD) {
        float acc = afb[c];
        #pragma unroll 8
        for (int k = 0; k < AA; ++k)
            acc += cfl[a][k] * wl[k * ORIGD + c];
        out1[(size_t)(p0 + a) * ORIGD + c] = acc;
    }
}

extern "C" void kernel_launch(void* const* d_in, const int* in_sizes, int n_in,
                              void* d_out, int out_size, void* d_ws, size_t ws_size,
                              hipStream_t stream) {
    (void)in_sizes; (void)n_in; (void)out_size;
    const float* atom_fea  = (const float*)d_in[0];
    const float* nbr_fea   = (const float*)d_in[1];
    const int*   nbr_idx   = (const int*)d_in[2];
    const int*   cidx      = (const int*)d_in[3];
    const float* emb_w     = (const float*)d_in[4];
    const float* fc_full_w = (const float*)d_in[5];
    // d_in[6] fc_full_b: cancelled by batchnorm, unused
    const float* bn1_g = (const float*)d_in[7];
    const float* bn1_b = (const float*)d_in[8];
    const float* bn2_g = (const float*)d_in[9];
    const float* bn2_b = (const float*)d_in[10];
    const float* adj_w = (const float*)d_in[11];
    const float* adj_b = (const float*)d_in[12];
    const float* fc1_w = (const float*)d_in[13];
    const float* fc1_b = (const float*)d_in[14];
    const float* af_w  = (const float*)d_in[15];
    const float* af_b  = (const float*)d_in[16];

    float* out0 = (float*)d_out;                        // edge_prob: 15e6 fp32
    float* out1 = out0 + (size_t)NB * NPCC * NPCC * 6;  // atom_feature: 4.6e6 fp32

    float* ws = (float*)d_ws;
    float* x      = ws;                          // 3.2e6 floats
    float* y0     = x + (size_t)NATOM * AA;      // 6.4e6
    float* y1     = y0 + (size_t)NATOM * 128;    // 6.4e6
    float* summed = y1 + (size_t)NATOM * 128;    // 3.2e6
    float* logp   = summed + (size_t)NATOM * AA; // 3e5
    float* stats1 = logp + (size_t)NATOM * 6;    // 256
    float* sc1    = stats1 + 256;                // 256
    float* stats2 = sc1 + 256;                   // 128
    float* sc2    = stats2 + 128;                // 128
    float* endf   = sc2 + 128;
    size_t base_bytes = (size_t)((char*)endf - (char*)d_ws);
    size_t gated_off = (base_bytes + 255) & ~(size_t)255;
    unsigned short* gated = (unsigned short*)((char*)d_ws + gated_off);
    bool store = ws_size >= gated_off + (size_t)NEDGE * 128 * 2;

    k_embed<<<NATOM / 4, 256, 0, stream>>>(atom_fea, emb_w, x);
    for (int layer = 0; layer < 3; ++layer) {
        const float* W  = fc_full_w + (size_t)layer * 169 * 128;
        const float* W2 = W + 128 * 128;
        k_zero<<<3, 256, 0, stream>>>(stats1, 768);
        k_y01<<<NATOM / 16, 256, 0, stream>>>(x, W, y0, y1);
        if (store)
            k_passA<true><<<NATOM / 16, 256, 0, stream>>>(y0, y1, nbr_fea, nbr_idx, W2, stats1, gated);
        else
            k_passA<false><<<NATOM / 16, 256, 0, stream>>>(y0, y1, nbr_fea, nbr_idx, W2, stats1, gated);
        k_sc1<<<1, 128, 0, stream>>>(stats1, bn1_g + layer * 128, bn1_b + layer * 128, sc1);
        if (store)
            k_passB<true><<<NATOM / 16, 256, 0, stream>>>(y0, y1, nbr_fea, nbr_idx, W2, sc1, gated, summed, stats2);
        else
            k_passB<false><<<NATOM / 16, 256, 0, stream>>>(y0, y1, nbr_fea, nbr_idx, W2, sc1, gated, summed, stats2);
        k_sc2<<<1, 64, 0, stream>>>(stats2, bn2_g + layer * 64, bn2_b + layer * 64, sc2);
        k_update<<<(NATOM * AA + 255) / 256, 256, 0, stream>>>(x, summed, sc2);
    }
    k_q<<<NATOM / 16, 256, 0, stream>>>(x, cidx, adj_w, adj_b, fc1_w, fc1_b, logp);
    k_edge<<<((NB * NPCC * NPCC * 6) / 4 + 255) / 256, 256, 0, stream>>>(logp, out0);
    k_af<<<NATOM / 2, 256, 0, stream>>>(x, cidx, af_w, af_b, out1);
}